// Round 14
// baseline (872.545 us; speedup 1.0000x reference)
//
#include <hip/hip_runtime.h>
#include <cstdint>
#include <cstddef>

typedef __attribute__((ext_vector_type(8))) short short8;
typedef __attribute__((ext_vector_type(8))) unsigned short ushort8;
typedef __attribute__((ext_vector_type(4))) float f32x4;

#define D64 64
static constexpr int kNU   = 215904;   // N_USERS
static constexpr int kNS   = 275904;   // N_S
static constexpr int kNT   = 265904;   // N_T
static constexpr int kNSH  = 4096;     // N_SHARED
static constexpr int kNNZ  = 2000000;
static constexpr float kTinv = 0.2f;   // 1/T
static constexpr int kBinCh = 8192;                          // edges per bin WG
static constexpr int kBGrid = (kNNZ + kBinCh - 1) / kBinCh;  // 245
static constexpr int kNBkS = (kNS + 511) / 512;              // 539 buckets (s)
static constexpr int kBStride = 4608;                        // padded slots per bucket
static constexpr int kBktCap = 6144;                         // LDS stage capacity
static constexpr int kColMask = 0x7FFFF;                     // 19 bits for col

__device__ __forceinline__ unsigned short f2bf(float x) {
  unsigned u = __builtin_bit_cast(unsigned, x);
  u += 0x7FFFu + ((u >> 16) & 1u);
  return (unsigned short)(u >> 16);
}
__device__ __forceinline__ float bf2f(unsigned short h) {
  return __builtin_bit_cast(float, (unsigned)h << 16);
}
__device__ __forceinline__ void ntst4(float* p, float4 v) {
  f32x4 vv = __builtin_bit_cast(f32x4, v);
  __builtin_nontemporal_store(vv, reinterpret_cast<f32x4*>(p));
}

// ===== init: bucket cursors to strided bases + rs/cs zero =====
__global__ void init_misc(int* __restrict__ bCur, float* __restrict__ rs, float* __restrict__ cs) {
  int i = blockIdx.x * 256 + threadIdx.x;
  if (i < 2048) bCur[i] = (i & 1023) * kBStride;
  if (i < kNSH) { rs[i] = 0.f; cs[i] = 0.f; }
}

// ====== MERGED: edge binning (blocks 0..2*kBGrid) || cvt_in (remaining blocks) ======
__global__ void cvt_bin(const int* __restrict__ s_idx, const float* __restrict__ s_vals,
                        const int* __restrict__ t_idx, const float* __restrict__ t_vals,
                        int* __restrict__ bCur,
                        int2* __restrict__ sCV, int2* __restrict__ tCV,
                        const float* __restrict__ su, const float* __restrict__ si,
                        const float* __restrict__ tu, const float* __restrict__ ti,
                        unsigned short* __restrict__ sub, unsigned short* __restrict__ tub,
                        float* __restrict__ out) {
  __shared__ int rows[kBinCh];
  __shared__ int cnt[544];
  int t = threadIdx.x;
  if (blockIdx.x < 2 * kBGrid) {
    int graph = (blockIdx.x >= kBGrid) ? 1 : 0;
    int chunk = blockIdx.x - graph * kBGrid;
    const int* idx = graph ? t_idx : s_idx;
    const float* vals = graph ? t_vals : s_vals;
    int2* CV = graph ? tCV : sCV;
    int* bc = bCur + graph * 1024;
    int e0 = chunk * kBinCh;
    int ecnt = min(kBinCh, kNNZ - e0);
    for (int b = t; b < 544; b += 256) cnt[b] = 0;
    __syncthreads();
    for (int k = t; k < ecnt; k += 256) {
      int r = idx[e0 + k];
      rows[k] = r;
      atomicAdd(&cnt[r >> 9], 1);
    }
    __syncthreads();
    for (int b = t; b < 544; b += 256) {
      int c = cnt[b];
      if (c) cnt[b] = atomicAdd(&bc[b], c);
    }
    __syncthreads();
    for (int k = t; k < ecnt; k += 256) {
      int r = rows[k];
      int p = atomicAdd(&cnt[r >> 9], 1);
      CV[p] = make_int2(idx[kNNZ + e0 + k] | ((r & 511) << 19),
                        __float_as_int(vals[e0 + k]));
    }
  } else {
    int g = (blockIdx.x - 2 * kBGrid) * 16 + (t >> 4);
    bool isS = g < kNS;
    int r = isS ? g : g - kNS;
    if (!isS && r >= kNT) return;
    const float* xu = isS ? su : tu;
    const float* xi = isS ? si : ti;
    int q = (t & 15) << 2;
    const float4 v = *reinterpret_cast<const float4*>(
        ((r < kNU) ? (xu + ((size_t)r << 6)) : (xi + ((size_t)(r - kNU) << 6))) + q);
    ntst4(out + (size_t)g * 256 + q, v);
    unsigned long long pk = (unsigned long long)f2bf(v.x) |
                            ((unsigned long long)f2bf(v.y) << 16) |
                            ((unsigned long long)f2bf(v.z) << 32) |
                            ((unsigned long long)f2bf(v.w) << 48);
    *reinterpret_cast<unsigned long long*>((isS ? sub : tub) + ((size_t)r << 6) + q) = pk;
  }
}

// ---- per-bucket CSR in LDS; writes Ptr/End (into padded EV) + ordered EV ----
__global__ void bucket_csr(const int2* __restrict__ sCV,
                           int* __restrict__ sPtr, int* __restrict__ sEnd, int2* __restrict__ sEV,
                           const int2* __restrict__ tCV,
                           int* __restrict__ tPtr, int* __restrict__ tEnd, int2* __restrict__ tEV,
                           const int* __restrict__ bCur) {
  const int n = blockIdx.y ? kNT : kNS;
  int b = blockIdx.x;
  int rb0 = b << 9;
  if (rb0 >= n) return;
  const int2* CV = blockIdx.y ? tCV : sCV;
  int* Ptr = blockIdx.y ? tPtr : sPtr;
  int* End = blockIdx.y ? tEnd : sEnd;
  int2* EV = blockIdx.y ? tEV : sEV;
  int base = b * kBStride;
  int endE = bCur[blockIdx.y * 1024 + b];
  int cnt = endE - base;
  __shared__ int cs[512];
  __shared__ int ps[256];
  __shared__ int2 stage[kBktCap];
  int t = threadIdx.x;
  cs[t] = 0; cs[t + 256] = 0;
  __syncthreads();
  for (int i = base + t; i < endE; i += 256)
    atomicAdd(&cs[CV[i].x >> 19], 1);
  __syncthreads();
  int c0 = cs[2 * t], c1 = cs[2 * t + 1];
  ps[t] = c0 + c1;
  __syncthreads();
  for (int off = 1; off < 256; off <<= 1) {
    int v = (t >= off) ? ps[t - off] : 0;
    __syncthreads();
    ps[t] += v;
    __syncthreads();
  }
  int pb = (t == 0) ? 0 : ps[t - 1];
  {
    int g0 = rb0 + 2 * t, g1 = g0 + 1;
    if (g0 < n) { Ptr[g0] = base + pb;      End[g0] = base + pb + c0; }
    if (g1 < n) { Ptr[g1] = base + pb + c0; End[g1] = base + pb + c0 + c1; }
  }
  cs[2 * t] = pb;
  cs[2 * t + 1] = pb + c0;
  __syncthreads();
  for (int i = base + t; i < endE; i += 256) {
    int2 cv = CV[i];
    int p = atomicAdd(&cs[cv.x >> 19], 1);
    stage[p] = make_int2(cv.x & kColMask, cv.y);
  }
  __syncthreads();
  for (int j = t; j < cnt; j += 256) EV[base + j] = stage[j];
}

// ====== layer-1 SpMM: single-phase batched-8 predicated bf16 gathers ======
__global__ void spmm1(const int* __restrict__ sPtr, const int* __restrict__ sEndA,
                      const int2* __restrict__ sEV,
                      const int* __restrict__ tPtr, const int* __restrict__ tEndA,
                      const int2* __restrict__ tEV,
                      const unsigned short* __restrict__ sub, const unsigned short* __restrict__ tub,
                      float* __restrict__ es1h, float* __restrict__ et1h,
                      unsigned short* __restrict__ es1b, unsigned short* __restrict__ et1b,
                      float* __restrict__ out) {
  int g = blockIdx.x * 32 + (threadIdx.x >> 3);
  bool isS = g < kNS;
  int r = isS ? g : g - kNS;
  if (!isS && r >= kNT) return;
  const int* Pp = isS ? sPtr : tPtr;
  const int* Pc = isS ? sEndA : tEndA;
  const int2* EV = isS ? sEV : tEV;
  const unsigned short* xb = isS ? sub : tub;
  int q = (threadIdx.x & 7) << 3;
  int beg = Pp[r], end = Pc[r];
  float acc[8] = {0.f, 0.f, 0.f, 0.f, 0.f, 0.f, 0.f, 0.f};
  int lim = end - 1;
  for (int i = beg; i < end; i += 8) {
    int2 ev[8];
#pragma unroll
    for (int k = 0; k < 8; ++k) ev[k] = EV[min(i + k, lim)];
    ushort8 xv[8];
#pragma unroll
    for (int k = 0; k < 8; ++k)
      xv[k] = *reinterpret_cast<const ushort8*>(xb + ((size_t)ev[k].x << 6) + q);
#pragma unroll
    for (int k = 0; k < 8; ++k) {
      float v = (i + k <= lim) ? __int_as_float(ev[k].y) : 0.f;
#pragma unroll
      for (int j = 0; j < 8; ++j)
        acc[j] = fmaf(v, bf2f((unsigned short)xv[k][j]), acc[j]);
    }
  }
  if (r < kNSH) {
    float* eh = isS ? es1h : et1h;
    *reinterpret_cast<float4*>(eh + ((size_t)r << 6) + q) =
        make_float4(acc[0], acc[1], acc[2], acc[3]);
    *reinterpret_cast<float4*>(eh + ((size_t)r << 6) + q + 4) =
        make_float4(acc[4], acc[5], acc[6], acc[7]);
  }
  {
    unsigned short* eb = isS ? es1b : et1b;
    ushort8 o;
#pragma unroll
    for (int j = 0; j < 8; ++j) o[j] = f2bf(acc[j]);
    *reinterpret_cast<ushort8*>(eb + ((size_t)r << 6) + q) = o;
  }
  float ss = 0.f;
#pragma unroll
  for (int j = 0; j < 8; ++j) ss += acc[j] * acc[j];
  ss += __shfl_xor(ss, 1); ss += __shfl_xor(ss, 2); ss += __shfl_xor(ss, 4);
  float inv = 1.f / fmaxf(sqrtf(ss), 1e-12f);
  if (r >= kNSH) {
    float* op = out + (size_t)g * 256 + 64 + q;
    ntst4(op, make_float4(acc[0] * inv, acc[1] * inv, acc[2] * inv, acc[3] * inv));
    ntst4(op + 4, make_float4(acc[4] * inv, acc[5] * inv, acc[6] * inv, acc[7] * inv));
  }
}

// ====== layers 2/3 SpMM: single-phase batched-8 predicated bf16 gathers ======
template <int WRITE_Y>
__global__ void spmm23(const int* __restrict__ sPtr, const int* __restrict__ sEndA,
                       const int2* __restrict__ sEV,
                       const int* __restrict__ tPtr, const int* __restrict__ tEndA,
                       const int2* __restrict__ tEV,
                       const unsigned short* __restrict__ xs, const unsigned short* __restrict__ xt,
                       unsigned short* __restrict__ ys, unsigned short* __restrict__ yt,
                       float* __restrict__ out, int coff) {
  int g = blockIdx.x * 32 + (threadIdx.x >> 3);
  bool isS = g < kNS;
  int r = isS ? g : g - kNS;
  if (!isS && r >= kNT) return;
  const int* Pp = isS ? sPtr : tPtr;
  const int* Pc = isS ? sEndA : tEndA;
  const int2* EV = isS ? sEV : tEV;
  const unsigned short* xb = isS ? xs : xt;
  int q = (threadIdx.x & 7) << 3;
  int beg = Pp[r], end = Pc[r];
  float acc[8] = {0.f, 0.f, 0.f, 0.f, 0.f, 0.f, 0.f, 0.f};
  int lim = end - 1;
  for (int i = beg; i < end; i += 8) {
    int2 ev[8];
#pragma unroll
    for (int k = 0; k < 8; ++k) ev[k] = EV[min(i + k, lim)];
    ushort8 xv[8];
#pragma unroll
    for (int k = 0; k < 8; ++k)
      xv[k] = *reinterpret_cast<const ushort8*>(xb + ((size_t)ev[k].x << 6) + q);
#pragma unroll
    for (int k = 0; k < 8; ++k) {
      float v = (i + k <= lim) ? __int_as_float(ev[k].y) : 0.f;
#pragma unroll
      for (int j = 0; j < 8; ++j)
        acc[j] = fmaf(v, bf2f((unsigned short)xv[k][j]), acc[j]);
    }
  }
  if (WRITE_Y) {
    unsigned short* yb = isS ? ys : yt;
    ushort8 o;
#pragma unroll
    for (int j = 0; j < 8; ++j) o[j] = f2bf(acc[j]);
    *reinterpret_cast<ushort8*>(yb + ((size_t)r << 6) + q) = o;
  }
  float ss = 0.f;
#pragma unroll
  for (int j = 0; j < 8; ++j) ss += acc[j] * acc[j];
  ss += __shfl_xor(ss, 1); ss += __shfl_xor(ss, 2); ss += __shfl_xor(ss, 4);
  float inv = 1.f / fmaxf(sqrtf(ss), 1e-12f);
  float* op = out + (size_t)g * 256 + coff + q;
  ntst4(op, make_float4(acc[0] * inv, acc[1] * inv, acc[2] * inv, acc[3] * inv));
  ntst4(op + 4, make_float4(acc[4] * inv, acc[5] * inv, acc[6] * inv, acc[7] * inv));
}

// ---------------- merged: tmp = src0@mapping (bf16 out) | cvt tgt0 -> bf16 row+col ----------------
__global__ void prep_inter(const float* __restrict__ A, const float* __restrict__ M,
                           unsigned short* __restrict__ tmpbf,
                           const float* __restrict__ Tg, unsigned short* __restrict__ rowmaj,
                           unsigned short* __restrict__ colmaj) {
  int t = threadIdx.x;
  if (blockIdx.y == 0) {
    __shared__ float Xs[64][65];
    __shared__ float As[16][65];
    int r0 = blockIdx.x * 16;
    int d = t & 63, rg = t >> 6;
    float acc[4] = {0.f, 0.f, 0.f, 0.f};
    for (int l = t; l < 1024; l += 256) {
      int r = l >> 4, c = (l & 15) << 2;
      float4 xv = *reinterpret_cast<const float4*>(M + (size_t)r * D64 + c);
      Xs[r][c] = xv.x; Xs[r][c + 1] = xv.y; Xs[r][c + 2] = xv.z; Xs[r][c + 3] = xv.w;
    }
    {
      int r = t >> 4, c = (t & 15) << 2;
      float4 av = *reinterpret_cast<const float4*>(A + (size_t)(r0 + r) * D64 + c);
      As[r][c] = av.x; As[r][c + 1] = av.y; As[r][c + 2] = av.z; As[r][c + 3] = av.w;
    }
    __syncthreads();
    for (int k = 0; k < 64; ++k) {
      float xv = Xs[k][d];
#pragma unroll
      for (int rr = 0; rr < 4; ++rr) acc[rr] += As[rg * 4 + rr][k] * xv;
    }
#pragma unroll
    for (int rr = 0; rr < 4; ++rr)
      tmpbf[(size_t)(r0 + rg * 4 + rr) * D64 + d] = f2bf(acc[rr]);
  } else {
    if (blockIdx.x >= 64) return;
    __shared__ unsigned short tile[64][72];
    int r0 = blockIdx.x * 64;
    int r = t >> 2, cq = (t & 3) << 4;
    unsigned short buf[16] __attribute__((aligned(16)));
#pragma unroll
    for (int j = 0; j < 16; j += 4) {
      float4 v = *reinterpret_cast<const float4*>(Tg + (size_t)(r0 + r) * D64 + cq + j);
      buf[j] = f2bf(v.x); buf[j + 1] = f2bf(v.y); buf[j + 2] = f2bf(v.z); buf[j + 3] = f2bf(v.w);
    }
#pragma unroll
    for (int j = 0; j < 16; ++j) tile[r][cq + j] = buf[j];
    *reinterpret_cast<ushort8*>(&rowmaj[(size_t)(r0 + r) * D64 + cq]) =
        *reinterpret_cast<ushort8*>(&buf[0]);
    *reinterpret_cast<ushort8*>(&rowmaj[(size_t)(r0 + r) * D64 + cq + 8]) =
        *reinterpret_cast<ushort8*>(&buf[8]);
    __syncthreads();
    int c = t >> 2, rq = (t & 3) << 4;
#pragma unroll
    for (int j = 0; j < 16; ++j) buf[j] = tile[rq + j][c];
    *reinterpret_cast<ushort8*>(&colmaj[(size_t)c * kNSH + r0 + rq]) =
        *reinterpret_cast<ushort8*>(&buf[0]);
    *reinterpret_cast<ushort8*>(&colmaj[(size_t)c * kNSH + r0 + rq + 8]) =
        *reinterpret_cast<ushort8*>(&buf[8]);
  }
}

// ======== MFMA: S=exp((tmp@tgt0^T)/T) -> Sbf, STbf (bf16), rs/cs (f32) ========
__global__ void expS_mfma(const unsigned short* __restrict__ Abf,
                          const unsigned short* __restrict__ Bbf,
                          unsigned short* __restrict__ Sbf, unsigned short* __restrict__ STbf,
                          float* __restrict__ rs, float* __restrict__ cs) {
  __shared__ unsigned short Cs[64][72];
  __shared__ float csred[4][64];
  int j0 = blockIdx.x * 64, i0 = blockIdx.y * 64;
  int t = threadIdx.x;
  int w = t >> 6, l = t & 63;
  int lr = l & 15, lk = (l >> 4) << 3;
  f32x4 acc[4] = {};
  const unsigned short* Ap = Abf + (size_t)(i0 + w * 16 + lr) * D64 + lk;
#pragma unroll
  for (int ks = 0; ks < 2; ++ks) {
    short8 a = *reinterpret_cast<const short8*>(Ap + ks * 32);
#pragma unroll
    for (int nt = 0; nt < 4; ++nt) {
      short8 b = *reinterpret_cast<const short8*>(
          Bbf + (size_t)(j0 + nt * 16 + lr) * D64 + ks * 32 + lk);
      acc[nt] = __builtin_amdgcn_mfma_f32_16x16x32_bf16(a, b, acc[nt], 0, 0, 0);
    }
  }
  float rowpart[4] = {0.f, 0.f, 0.f, 0.f};
#pragma unroll
  for (int nt = 0; nt < 4; ++nt) {
    float colpart = 0.f;
#pragma unroll
    for (int rg = 0; rg < 4; ++rg) {
      float e = __expf(acc[nt][rg] * kTinv);
      acc[nt][rg] = e;
      rowpart[rg] += e;
      colpart += e;
      Cs[w * 16 + (l >> 4) * 4 + rg][nt * 16 + lr] = f2bf(e);
    }
    float v = colpart;
    v += __shfl_xor(v, 16); v += __shfl_xor(v, 32);
    if (l < 16) csred[w][nt * 16 + l] = v;
  }
#pragma unroll
  for (int rg = 0; rg < 4; ++rg) {
    float v = rowpart[rg];
    v += __shfl_xor(v, 1); v += __shfl_xor(v, 2);
    v += __shfl_xor(v, 4); v += __shfl_xor(v, 8);
    if (lr == 0) atomicAdd(&rs[i0 + w * 16 + (l >> 4) * 4 + rg], v);
  }
  __syncthreads();
  if (t < 64) atomicAdd(&cs[j0 + t], csred[0][t] + csred[1][t] + csred[2][t] + csred[3][t]);
  {
    int r = t >> 2, cq = (t & 3) << 4;
    ushort8 v0 = *reinterpret_cast<const ushort8*>(&Cs[r][cq]);
    ushort8 v1 = *reinterpret_cast<const ushort8*>(&Cs[r][cq + 8]);
    *reinterpret_cast<ushort8*>(&Sbf[(size_t)(i0 + r) * kNSH + j0 + cq]) = v0;
    *reinterpret_cast<ushort8*>(&Sbf[(size_t)(i0 + r) * kNSH + j0 + cq + 8]) = v1;
    int c = t >> 2, rq = (t & 3) << 4;
    unsigned short buf[16] __attribute__((aligned(16)));
#pragma unroll
    for (int j = 0; j < 16; ++j) buf[j] = Cs[rq + j][c];
    *reinterpret_cast<ushort8*>(&STbf[(size_t)(j0 + c) * kNSH + i0 + rq]) =
        *reinterpret_cast<ushort8*>(&buf[0]);
    *reinterpret_cast<ushort8*>(&STbf[(size_t)(j0 + c) * kNSH + i0 + rq + 8]) =
        *reinterpret_cast<ushort8*>(&buf[8]);
  }
}

// ======== MERGED: Ds/Dt row reduces (blocks 0..8191) || head sgemm Sbf@tgtT (blocks 8192..8447) ========
__global__ void rowred_sgemm(const unsigned short* __restrict__ Sbf,
                             const unsigned short* __restrict__ STbf,
                             const float* __restrict__ rs, const float* __restrict__ cs,
                             float* __restrict__ Ds, float* __restrict__ Dt,
                             const unsigned short* __restrict__ tgtT, float* __restrict__ partA) {
  int t = threadIdx.x;
  if (blockIdx.x < 8192) {
    int graph = blockIdx.x >> 12;
    int i = blockIdx.x & 4095;
    const unsigned short* Sb = graph ? STbf : Sbf;
    const float* wv = graph ? rs : cs;
    float* outp = graph ? Dt : Ds;
    const unsigned short* row = Sb + (size_t)i * kNSH;
    float acc = 0.f;
    for (int j0 = t * 8; j0 < kNSH; j0 += 2048) {
      short8 v = *reinterpret_cast<const short8*>(row + j0);
#pragma unroll
      for (int j = 0; j < 8; ++j) acc += bf2f((unsigned short)v[j]) * wv[j0 + j];
    }
#pragma unroll
    for (int o = 32; o; o >>= 1) acc += __shfl_xor(acc, o);
    __shared__ float red[4];
    if ((t & 63) == 0) red[t >> 6] = acc;
    __syncthreads();
    if (t == 0) outp[i] = red[0] + red[1] + red[2] + red[3] + 1.f;
  } else {
    int bid = blockIdx.x - 8192;
    int wv = t >> 6, l = t & 63;
    int lr = l & 15, lk = (l >> 4) << 3;
    int m0 = (bid & 63) * 64 + wv * 16;
    int k0 = (bid >> 6) * 1024;
    f32x4 acc[4] = {};
    const unsigned short* Ap = Sbf + (size_t)(m0 + lr) * kNSH + k0 + lk;
    const unsigned short* Xp = tgtT + (size_t)lr * kNSH + k0 + lk;
    for (int ks = 0; ks < 32; ++ks) {
      short8 a = *reinterpret_cast<const short8*>(Ap + ks * 32);
#pragma unroll
      for (int nt = 0; nt < 4; ++nt) {
        short8 b = *reinterpret_cast<const short8*>(Xp + (size_t)nt * 16 * kNSH + ks * 32);
        acc[nt] = __builtin_amdgcn_mfma_f32_16x16x32_bf16(a, b, acc[nt], 0, 0, 0);
      }
    }
    float* Pp = partA + ((size_t)(bid >> 6) * kNSH + m0) * D64;
#pragma unroll
    for (int nt = 0; nt < 4; ++nt)
#pragma unroll
      for (int rg = 0; rg < 4; ++rg)
        Pp[(size_t)((l >> 4) * 4 + rg) * D64 + nt * 16 + lr] = acc[nt][rg];
  }
}

// ======== dual-chain split-K MFMA skinny GEMM ========
__global__ void sgemm_bf(const unsigned short* __restrict__ aA, const unsigned short* __restrict__ xA,
                         float* __restrict__ pA,
                         const unsigned short* __restrict__ aB, const unsigned short* __restrict__ xB,
                         float* __restrict__ pB) {
  const unsigned short* A = (blockIdx.z == 0) ? aA : aB;
  const unsigned short* X = (blockIdx.z == 0) ? xA : xB;
  float* P = (blockIdx.z == 0) ? pA : pB;
  int t = threadIdx.x;
  int w = t >> 6, l = t & 63;
  int lr = l & 15, lk = (l >> 4) << 3;
  int m0 = blockIdx.x * 64 + w * 16;
  int k0 = blockIdx.y * 1024;
  f32x4 acc[4] = {};
  const unsigned short* Ap = A + (size_t)(m0 + lr) * kNSH + k0 + lk;
  const unsigned short* Xp = X + (size_t)lr * kNSH + k0 + lk;
  for (int ks = 0; ks < 32; ++ks) {
    short8 a = *reinterpret_cast<const short8*>(Ap + ks * 32);
#pragma unroll
    for (int nt = 0; nt < 4; ++nt) {
      short8 b = *reinterpret_cast<const short8*>(Xp + (size_t)nt * 16 * kNSH + ks * 32);
      acc[nt] = __builtin_amdgcn_mfma_f32_16x16x32_bf16(a, b, acc[nt], 0, 0, 0);
    }
  }
  float* Pp = P + ((size_t)blockIdx.y * kNSH + m0) * D64;
#pragma unroll
  for (int nt = 0; nt < 4; ++nt)
#pragma unroll
    for (int rg = 0; rg < 4; ++rg)
      Pp[(size_t)((l >> 4) * 4 + rg) * D64 + nt * 16 + lr] = acc[nt][rg];
}

// ======== split-K reduce + epilogue (dual-chain via blockIdx.y) ========
template <int EPI>
__global__ void red_epi(const float* __restrict__ pA, const float* __restrict__ addA,
                        const float* __restrict__ scA, float* __restrict__ outA,
                        unsigned short* __restrict__ outTA, const float* __restrict__ rawA,
                        unsigned short* __restrict__ rmA,
                        const float* __restrict__ pB, const float* __restrict__ addB,
                        const float* __restrict__ scB, float* __restrict__ outB,
                        unsigned short* __restrict__ outTB, const float* __restrict__ rawB,
                        unsigned short* __restrict__ rmB,
                        float* __restrict__ gout) {
  const float* p = (blockIdx.y == 0) ? pA : pB;
  const float* add = (blockIdx.y == 0) ? addA : addB;
  const float* sc = (blockIdx.y == 0) ? scA : scB;
  float* out = (blockIdx.y == 0) ? outA : outB;
  unsigned short* outT = (blockIdx.y == 0) ? outTA : outTB;
  const float* raw = (blockIdx.y == 0) ? rawA : rawB;
  unsigned short* rm = (blockIdx.y == 0) ? rmA : rmB;
  __shared__ unsigned short tile[64][4];
  int t = threadIdx.x;
  int d = t & 63, rl = t >> 6;
  int r = blockIdx.x * 4 + rl;
  size_t off = (size_t)r * D64 + d;
  const size_t SL = (size_t)kNSH * D64;
  float s = p[off] + p[SL + off] + p[2 * SL + off] + p[3 * SL + off];
  float v;
  if (EPI == 0) {
    v = s;
  } else if (EPI == 1) {
    v = add[off] + s / fmaxf(sc[r], 1e-12f);
    out[off] = v;
  } else {
    float x = fmaxf((s + add[off]) / sc[r], 0.f);
    float ss = x * x;
#pragma unroll
    for (int o = 32; o; o >>= 1) ss += __shfl_xor(ss, o);
    v = x / fmaxf(sqrtf(ss), 1e-12f);
    if (EPI == 2) out[off] = v;
    else {
      float fv = 0.5f * (raw[off] + v);
      rm[off] = f2bf(fv);
      float s2 = fv * fv;
#pragma unroll
      for (int o = 32; o; o >>= 1) s2 += __shfl_xor(s2, o);
      float nv = fv / fmaxf(sqrtf(s2), 1e-12f);
      size_t grow0 = (blockIdx.y == 0) ? 0 : (size_t)kNS;
      __builtin_nontemporal_store(nv, &gout[(grow0 + (size_t)r) * 256 + 64 + d]);
    }
  }
  if (EPI != 3) {
    tile[d][rl] = f2bf(v);
    __syncthreads();
    if (t < 64) {
      unsigned long long pk;
      unsigned short* pp = reinterpret_cast<unsigned short*>(&pk);
      pp[0] = tile[t][0]; pp[1] = tile[t][1]; pp[2] = tile[t][2]; pp[3] = tile[t][3];
      *reinterpret_cast<unsigned long long*>(&outT[(size_t)t * kNSH + blockIdx.x * 4]) = pk;
    }
  }
}

extern "C" void kernel_launch(void* const* d_in, const int* in_sizes, int n_in,
                              void* d_out, int out_size, void* d_ws, size_t ws_size,
                              hipStream_t stream) {
  const float* src_user = (const float*)d_in[0];
  const float* tgt_user = (const float*)d_in[1];
  const float* src_item = (const float*)d_in[2];
  const float* tgt_item = (const float*)d_in[3];
  const float* mapping  = (const float*)d_in[4];
  const float* s_vals   = (const float*)d_in[5];
  const float* t_vals   = (const float*)d_in[6];
  const int*   s_idx    = (const int*)d_in[7];
  const int*   t_idx    = (const int*)d_in[8];
  float* out = (float*)d_out;

  float* w = (float*)d_ws;
  size_t o = 0;
  float* es1h = w + o; o += (size_t)kNSH * D64;
  float* et1h = w + o; o += (size_t)kNSH * D64;
  float* src2 = w + o; o += (size_t)kNSH * D64;
  float* tgt2 = w + o; o += (size_t)kNSH * D64;
  float* itS  = w + o; o += (size_t)kNSH * D64;
  float* itT  = w + o; o += (size_t)kNSH * D64;
  float* partA = w + o; o += (size_t)4 * kNSH * D64;
  float* partB = w + o; o += (size_t)4 * kNSH * D64;
  float* rs = w + o; o += kNSH;
  float* cs = w + o; o += kNSH;
  float* Ds = w + o; o += kNSH;
  float* Dt = w + o; o += kNSH;
  // bf16 region
  unsigned short* ub = (unsigned short*)(w + o);
  size_t uo = 0;
  unsigned short* Sbf   = ub + uo; uo += (size_t)kNSH * kNSH;
  unsigned short* STbf  = ub + uo; uo += (size_t)kNSH * kNSH;
  unsigned short* tmpbf = ub + uo; uo += (size_t)kNSH * D64;
  unsigned short* tgtbf = ub + uo; uo += (size_t)kNSH * D64;
  unsigned short* tgtT  = ub + uo; uo += (size_t)kNSH * D64;
  unsigned short* src2T = ub + uo; uo += (size_t)kNSH * D64;
  unsigned short* tgt2T = ub + uo; uo += (size_t)kNSH * D64;
  unsigned short* itST  = ub + uo; uo += (size_t)kNSH * D64;
  unsigned short* itTT  = ub + uo; uo += (size_t)kNSH * D64;
  unsigned short* ybAT  = ub + uo; uo += (size_t)kNSH * D64;
  unsigned short* ybBT  = ub + uo; uo += (size_t)kNSH * D64;
  unsigned short* sub   = ub + uo; uo += (size_t)kNS * D64;
  unsigned short* tub   = ub + uo; uo += (size_t)kNT * D64;
  unsigned short* es1b  = ub + uo; uo += (size_t)kNS * D64;
  unsigned short* et1b  = ub + uo; uo += (size_t)kNT * D64;
  unsigned short* es2b  = ub + uo; uo += (size_t)kNS * D64;
  unsigned short* et2b  = ub + uo; uo += (size_t)kNT * D64;
  // int region
  int* iw = (int*)(ub + ((uo + 1) & ~(size_t)1));
  size_t io = 0;
  int* sPtr = iw + io; io += kNS;
  int* sEnd = iw + io; io += kNS;
  int* tPtr = iw + io; io += kNT;
  int* tEnd = iw + io; io += kNT;
  int* bCur = iw + io; io += 2048;
  io = (io + 1) & ~(size_t)1;
  const size_t kPad = (size_t)544 * kBStride;
  int2* sEV = (int2*)(iw + io); io += 2 * kPad;
  int2* tEV = (int2*)(iw + io); io += 2 * kPad;
  int2* sCV = (int2*)(iw + io); io += 2 * kPad;
  int2* tCV = (int2*)(iw + io); io += 2 * kPad;

  // ---- CSR build + input cvt (merged) ----
  init_misc<<<16, 256, 0, stream>>>(bCur, rs, cs);
  cvt_bin<<<2 * kBGrid + (kNS + kNT + 15) / 16, 256, 0, stream>>>(
      s_idx, s_vals, t_idx, t_vals, bCur, sCV, tCV,
      src_user, src_item, tgt_user, tgt_item, sub, tub, out);
  bucket_csr<<<dim3(kNBkS, 2), 256, 0, stream>>>(sCV, sPtr, sEnd, sEV,
                                                 tCV, tPtr, tEnd, tEV, bCur);

  // ---- layer 1 spmm ----
  spmm1<<<(kNS + kNT + 31) / 32, 256, 0, stream>>>(sPtr, sEnd, sEV, tPtr, tEnd, tEV,
                                                   sub, tub, es1h, et1h, es1b, et1b, out);

  // ---- inter block ----
  prep_inter<<<dim3(256, 2), 256, 0, stream>>>(es1h, mapping, tmpbf, et1h, tgtbf, tgtT);
  expS_mfma<<<dim3(64, 64), 256, 0, stream>>>(tmpbf, tgtbf, Sbf, STbf, rs, cs);
  // Ds/Dt reduces merged with head sgemm (Sbf @ tgtT -> partA)
  rowred_sgemm<<<8192 + 256, 256, 0, stream>>>(Sbf, STbf, rs, cs, Ds, Dt, tgtT, partA);
  red_epi<1><<<dim3(1024, 1), 256, 0, stream>>>(partA, es1h, rs, src2, src2T, nullptr, nullptr,
                                                partA, es1h, rs, src2, src2T, nullptr, nullptr, out);
  // tgt2 = tgt0 + (S^T@src2)/cs
  sgemm_bf<<<dim3(64, 4, 1), 256, 0, stream>>>(STbf, src2T, partA, STbf, src2T, partA);
  red_epi<1><<<dim3(1024, 1), 256, 0, stream>>>(partA, et1h, cs, tgt2, tgt2T, nullptr, nullptr,
                                                partA, et1h, cs, tgt2, tgt2T, nullptr, nullptr, out);
  // 3 propagation iterations, dual-chain batched split-K
  float* paF = src2; unsigned short* paT = src2T;
  float* pbF = itS;  unsigned short* pbT = itST;
  float* qaF = tgt2; unsigned short* qaT = tgt2T;
  float* qbF = itT;  unsigned short* qbT = itTT;
  for (int itn = 0; itn < 3; ++itn) {
    sgemm_bf<<<dim3(64, 4, 2), 256, 0, stream>>>(STbf, paT, partA, Sbf, qaT, partB);
    red_epi<0><<<dim3(1024, 2), 256, 0, stream>>>(
        partA, nullptr, nullptr, nullptr, ybAT, nullptr, nullptr,
        partB, nullptr, nullptr, nullptr, ybBT, nullptr, nullptr, out);
    sgemm_bf<<<dim3(64, 4, 2), 256, 0, stream>>>(Sbf, ybAT, partA, STbf, ybBT, partB);
    if (itn < 2) {
      red_epi<2><<<dim3(1024, 2), 256, 0, stream>>>(
          partA, paF, Ds, pbF, pbT, nullptr, nullptr,
          partB, qaF, Dt, qbF, qbT, nullptr, nullptr, out);
      float* tf = paF; paF = pbF; pbF = tf;
      unsigned short* tt = paT; paT = pbT; pbT = tt;
      tf = qaF; qaF = qbF; qbF = tf;
      tt = qaT; qaT = qbT; qbT = tt;
    } else {
      red_epi<3><<<dim3(1024, 2), 256, 0, stream>>>(
          partA, paF, Ds, nullptr, nullptr, es1h, es1b,
          partB, qaF, Dt, nullptr, nullptr, et1h, et1b, out);
    }
  }

  // ---- layer 2 ----
  spmm23<1><<<(kNS + kNT + 31) / 32, 256, 0, stream>>>(sPtr, sEnd, sEV, tPtr, tEnd, tEV,
                                                       es1b, et1b, es2b, et2b, out, 128);
  // ---- layer 3 ----
  spmm23<0><<<(kNS + kNT + 31) / 32, 256, 0, stream>>>(sPtr, sEnd, sEV, tPtr, tEnd, tEV,
                                                       es2b, et2b, nullptr, nullptr, out, 192);
}

// Round 15
// 860.407 us; speedup vs baseline: 1.0141x; 1.0141x over previous
//
#include <hip/hip_runtime.h>
#include <cstdint>
#include <cstddef>

typedef __attribute__((ext_vector_type(8))) short short8;
typedef __attribute__((ext_vector_type(8))) unsigned short ushort8;
typedef __attribute__((ext_vector_type(4))) float f32x4;

#define D64 64
static constexpr int kNU   = 215904;   // N_USERS
static constexpr int kNS   = 275904;   // N_S
static constexpr int kNT   = 265904;   // N_T
static constexpr int kNSH  = 4096;     // N_SHARED
static constexpr int kNNZ  = 2000000;
static constexpr float kTinv = 0.2f;   // 1/T
static constexpr int kBinCh = 8192;                          // edges per bin WG
static constexpr int kNBkS = (kNS + 511) / 512;              // 539 buckets (s)
static constexpr int kBStride = 4608;                        // padded slots per bucket (+14 sigma)
static constexpr int kBktCap = 6144;                         // LDS stage capacity
static constexpr int kColMask = 0x7FFFF;                     // 19 bits for col

__device__ __forceinline__ unsigned short f2bf(float x) {
  unsigned u = __builtin_bit_cast(unsigned, x);
  u += 0x7FFFu + ((u >> 16) & 1u);
  return (unsigned short)(u >> 16);
}
__device__ __forceinline__ float bf2f(unsigned short h) {
  return __builtin_bit_cast(float, (unsigned)h << 16);
}
__device__ __forceinline__ void ntst4(float* p, float4 v) {
  f32x4 vv = __builtin_bit_cast(f32x4, v);
  __builtin_nontemporal_store(vv, reinterpret_cast<f32x4*>(p));
}

// ===== init: bucket cursors to strided bases + rs/cs zero =====
__global__ void init_misc(int* __restrict__ bCur, float* __restrict__ rs, float* __restrict__ cs) {
  int i = blockIdx.x * 256 + threadIdx.x;
  if (i < 2048) bCur[i] = (i & 1023) * kBStride;
  if (i < kNSH) { rs[i] = 0.f; cs[i] = 0.f; }
}

// ---- phase a: LDS-aggregated binning by row>>9 into fixed-stride bucket regions ----
// CV.x = col | (rowInBucket << 19), CV.y = val bits
__global__ void bin_lds(const int* __restrict__ s_idx, const float* __restrict__ s_vals,
                        const int* __restrict__ t_idx, const float* __restrict__ t_vals,
                        int* __restrict__ bCur,
                        int2* __restrict__ sCV, int2* __restrict__ tCV) {
  const int* idx = blockIdx.y ? t_idx : s_idx;
  const float* vals = blockIdx.y ? t_vals : s_vals;
  int2* CV = blockIdx.y ? tCV : sCV;
  int* bc = bCur + blockIdx.y * 1024;
  __shared__ int rows[kBinCh];
  __shared__ int cnt[544];
  int t = threadIdx.x;
  int e0 = blockIdx.x * kBinCh;
  int ecnt = min(kBinCh, kNNZ - e0);
  for (int b = t; b < 544; b += 256) cnt[b] = 0;
  __syncthreads();
  for (int k = t; k < ecnt; k += 256) {
    int r = idx[e0 + k];
    rows[k] = r;
    atomicAdd(&cnt[r >> 9], 1);
  }
  __syncthreads();
  for (int b = t; b < 544; b += 256) {
    int c = cnt[b];
    if (c) cnt[b] = atomicAdd(&bc[b], c);
  }
  __syncthreads();
  for (int k = t; k < ecnt; k += 256) {
    int r = rows[k];
    int p = atomicAdd(&cnt[r >> 9], 1);
    CV[p] = make_int2(idx[kNNZ + e0 + k] | ((r & 511) << 19),
                      __float_as_int(vals[e0 + k]));
  }
}

// ---- phase b: per-bucket CSR in LDS; writes Ptr/End (into padded EV) + ordered EV ----
__global__ void bucket_csr(const int2* __restrict__ sCV,
                           int* __restrict__ sPtr, int* __restrict__ sEnd, int2* __restrict__ sEV,
                           const int2* __restrict__ tCV,
                           int* __restrict__ tPtr, int* __restrict__ tEnd, int2* __restrict__ tEV,
                           const int* __restrict__ bCur) {
  const int n = blockIdx.y ? kNT : kNS;
  int b = blockIdx.x;
  int rb0 = b << 9;
  if (rb0 >= n) return;
  const int2* CV = blockIdx.y ? tCV : sCV;
  int* Ptr = blockIdx.y ? tPtr : sPtr;
  int* End = blockIdx.y ? tEnd : sEnd;
  int2* EV = blockIdx.y ? tEV : sEV;
  int base = b * kBStride;
  int endE = bCur[blockIdx.y * 1024 + b];  // base + count
  int cnt = endE - base;
  __shared__ int cs[512];
  __shared__ int ps[256];
  __shared__ int2 stage[kBktCap];
  int t = threadIdx.x;
  cs[t] = 0; cs[t + 256] = 0;
  __syncthreads();
  for (int i = base + t; i < endE; i += 256)
    atomicAdd(&cs[CV[i].x >> 19], 1);
  __syncthreads();
  int c0 = cs[2 * t], c1 = cs[2 * t + 1];
  ps[t] = c0 + c1;
  __syncthreads();
  for (int off = 1; off < 256; off <<= 1) {
    int v = (t >= off) ? ps[t - off] : 0;
    __syncthreads();
    ps[t] += v;
    __syncthreads();
  }
  int pb = (t == 0) ? 0 : ps[t - 1];
  {
    int g0 = rb0 + 2 * t, g1 = g0 + 1;
    if (g0 < n) { Ptr[g0] = base + pb;      End[g0] = base + pb + c0; }
    if (g1 < n) { Ptr[g1] = base + pb + c0; End[g1] = base + pb + c0 + c1; }
  }
  cs[2 * t] = pb;
  cs[2 * t + 1] = pb + c0;
  __syncthreads();
  for (int i = base + t; i < endE; i += 256) {
    int2 cv = CV[i];
    int p = atomicAdd(&cs[cv.x >> 19], 1);
    stage[p] = make_int2(cv.x & kColMask, cv.y);
  }
  __syncthreads();
  for (int j = t; j < cnt; j += 256) EV[base + j] = stage[j];
}

// ====== cvt_in: raw concat -> out block 0 (exact f32, NT) + unified bf16 copies ======
__global__ void cvt_in(const float* __restrict__ su, const float* __restrict__ si,
                       const float* __restrict__ tu, const float* __restrict__ ti,
                       unsigned short* __restrict__ sub, unsigned short* __restrict__ tub,
                       float* __restrict__ out) {
  int g = blockIdx.x * 16 + (threadIdx.x >> 4);
  bool isS = g < kNS;
  int r = isS ? g : g - kNS;
  if (!isS && r >= kNT) return;
  const float* xu = isS ? su : tu;
  const float* xi = isS ? si : ti;
  int q = (threadIdx.x & 15) << 2;
  const float4 v = *reinterpret_cast<const float4*>(
      ((r < kNU) ? (xu + ((size_t)r << 6)) : (xi + ((size_t)(r - kNU) << 6))) + q);
  ntst4(out + (size_t)g * 256 + q, v);
  unsigned long long pk = (unsigned long long)f2bf(v.x) |
                          ((unsigned long long)f2bf(v.y) << 16) |
                          ((unsigned long long)f2bf(v.z) << 32) |
                          ((unsigned long long)f2bf(v.w) << 48);
  *reinterpret_cast<unsigned long long*>((isS ? sub : tub) + ((size_t)r << 6) + q) = pk;
}

// ====== layer-1 SpMM: single-phase batched-8 predicated bf16 gathers ======
__global__ void spmm1(const int* __restrict__ sPtr, const int* __restrict__ sEndA,
                      const int2* __restrict__ sEV,
                      const int* __restrict__ tPtr, const int* __restrict__ tEndA,
                      const int2* __restrict__ tEV,
                      const unsigned short* __restrict__ sub, const unsigned short* __restrict__ tub,
                      float* __restrict__ es1h, float* __restrict__ et1h,
                      unsigned short* __restrict__ es1b, unsigned short* __restrict__ et1b,
                      float* __restrict__ out) {
  int g = blockIdx.x * 32 + (threadIdx.x >> 3);
  bool isS = g < kNS;
  int r = isS ? g : g - kNS;
  if (!isS && r >= kNT) return;
  const int* Pp = isS ? sPtr : tPtr;
  const int* Pc = isS ? sEndA : tEndA;
  const int2* EV = isS ? sEV : tEV;
  const unsigned short* xb = isS ? sub : tub;
  int q = (threadIdx.x & 7) << 3;
  int beg = Pp[r], end = Pc[r];
  float acc[8] = {0.f, 0.f, 0.f, 0.f, 0.f, 0.f, 0.f, 0.f};
  int lim = end - 1;
  for (int i = beg; i < end; i += 8) {
    int2 ev[8];
#pragma unroll
    for (int k = 0; k < 8; ++k) ev[k] = EV[min(i + k, lim)];
    ushort8 xv[8];
#pragma unroll
    for (int k = 0; k < 8; ++k)
      xv[k] = *reinterpret_cast<const ushort8*>(xb + ((size_t)ev[k].x << 6) + q);
#pragma unroll
    for (int k = 0; k < 8; ++k) {
      float v = (i + k <= lim) ? __int_as_float(ev[k].y) : 0.f;
#pragma unroll
      for (int j = 0; j < 8; ++j)
        acc[j] = fmaf(v, bf2f((unsigned short)xv[k][j]), acc[j]);
    }
  }
  if (r < kNSH) {
    float* eh = isS ? es1h : et1h;
    *reinterpret_cast<float4*>(eh + ((size_t)r << 6) + q) =
        make_float4(acc[0], acc[1], acc[2], acc[3]);
    *reinterpret_cast<float4*>(eh + ((size_t)r << 6) + q + 4) =
        make_float4(acc[4], acc[5], acc[6], acc[7]);
  }
  {
    unsigned short* eb = isS ? es1b : et1b;
    ushort8 o;
#pragma unroll
    for (int j = 0; j < 8; ++j) o[j] = f2bf(acc[j]);
    *reinterpret_cast<ushort8*>(eb + ((size_t)r << 6) + q) = o;
  }
  float ss = 0.f;
#pragma unroll
  for (int j = 0; j < 8; ++j) ss += acc[j] * acc[j];
  ss += __shfl_xor(ss, 1); ss += __shfl_xor(ss, 2); ss += __shfl_xor(ss, 4);
  float inv = 1.f / fmaxf(sqrtf(ss), 1e-12f);
  if (r >= kNSH) {
    float* op = out + (size_t)g * 256 + 64 + q;
    ntst4(op, make_float4(acc[0] * inv, acc[1] * inv, acc[2] * inv, acc[3] * inv));
    ntst4(op + 4, make_float4(acc[4] * inv, acc[5] * inv, acc[6] * inv, acc[7] * inv));
  }
}

// ====== layers 2/3 SpMM: single-phase batched-8 predicated bf16 gathers ======
template <int WRITE_Y>
__global__ void spmm23(const int* __restrict__ sPtr, const int* __restrict__ sEndA,
                       const int2* __restrict__ sEV,
                       const int* __restrict__ tPtr, const int* __restrict__ tEndA,
                       const int2* __restrict__ tEV,
                       const unsigned short* __restrict__ xs, const unsigned short* __restrict__ xt,
                       unsigned short* __restrict__ ys, unsigned short* __restrict__ yt,
                       float* __restrict__ out, int coff) {
  int g = blockIdx.x * 32 + (threadIdx.x >> 3);
  bool isS = g < kNS;
  int r = isS ? g : g - kNS;
  if (!isS && r >= kNT) return;
  const int* Pp = isS ? sPtr : tPtr;
  const int* Pc = isS ? sEndA : tEndA;
  const int2* EV = isS ? sEV : tEV;
  const unsigned short* xb = isS ? xs : xt;
  int q = (threadIdx.x & 7) << 3;
  int beg = Pp[r], end = Pc[r];
  float acc[8] = {0.f, 0.f, 0.f, 0.f, 0.f, 0.f, 0.f, 0.f};
  int lim = end - 1;
  for (int i = beg; i < end; i += 8) {
    int2 ev[8];
#pragma unroll
    for (int k = 0; k < 8; ++k) ev[k] = EV[min(i + k, lim)];
    ushort8 xv[8];
#pragma unroll
    for (int k = 0; k < 8; ++k)
      xv[k] = *reinterpret_cast<const ushort8*>(xb + ((size_t)ev[k].x << 6) + q);
#pragma unroll
    for (int k = 0; k < 8; ++k) {
      float v = (i + k <= lim) ? __int_as_float(ev[k].y) : 0.f;
#pragma unroll
      for (int j = 0; j < 8; ++j)
        acc[j] = fmaf(v, bf2f((unsigned short)xv[k][j]), acc[j]);
    }
  }
  if (WRITE_Y) {
    unsigned short* yb = isS ? ys : yt;
    ushort8 o;
#pragma unroll
    for (int j = 0; j < 8; ++j) o[j] = f2bf(acc[j]);
    *reinterpret_cast<ushort8*>(yb + ((size_t)r << 6) + q) = o;
  }
  float ss = 0.f;
#pragma unroll
  for (int j = 0; j < 8; ++j) ss += acc[j] * acc[j];
  ss += __shfl_xor(ss, 1); ss += __shfl_xor(ss, 2); ss += __shfl_xor(ss, 4);
  float inv = 1.f / fmaxf(sqrtf(ss), 1e-12f);
  float* op = out + (size_t)g * 256 + coff + q;
  ntst4(op, make_float4(acc[0] * inv, acc[1] * inv, acc[2] * inv, acc[3] * inv));
  ntst4(op + 4, make_float4(acc[4] * inv, acc[5] * inv, acc[6] * inv, acc[7] * inv));
}

// ---------------- merged: tmp = src0@mapping (bf16 out) | cvt tgt0 -> bf16 row+col ----------------
__global__ void prep_inter(const float* __restrict__ A, const float* __restrict__ M,
                           unsigned short* __restrict__ tmpbf,
                           const float* __restrict__ Tg, unsigned short* __restrict__ rowmaj,
                           unsigned short* __restrict__ colmaj) {
  int t = threadIdx.x;
  if (blockIdx.y == 0) {
    __shared__ float Xs[64][65];
    __shared__ float As[16][65];
    int r0 = blockIdx.x * 16;
    int d = t & 63, rg = t >> 6;
    float acc[4] = {0.f, 0.f, 0.f, 0.f};
    for (int l = t; l < 1024; l += 256) {
      int r = l >> 4, c = (l & 15) << 2;
      float4 xv = *reinterpret_cast<const float4*>(M + (size_t)r * D64 + c);
      Xs[r][c] = xv.x; Xs[r][c + 1] = xv.y; Xs[r][c + 2] = xv.z; Xs[r][c + 3] = xv.w;
    }
    {
      int r = t >> 4, c = (t & 15) << 2;
      float4 av = *reinterpret_cast<const float4*>(A + (size_t)(r0 + r) * D64 + c);
      As[r][c] = av.x; As[r][c + 1] = av.y; As[r][c + 2] = av.z; As[r][c + 3] = av.w;
    }
    __syncthreads();
    for (int k = 0; k < 64; ++k) {
      float xv = Xs[k][d];
#pragma unroll
      for (int rr = 0; rr < 4; ++rr) acc[rr] += As[rg * 4 + rr][k] * xv;
    }
#pragma unroll
    for (int rr = 0; rr < 4; ++rr)
      tmpbf[(size_t)(r0 + rg * 4 + rr) * D64 + d] = f2bf(acc[rr]);
  } else {
    if (blockIdx.x >= 64) return;
    __shared__ unsigned short tile[64][72];
    int r0 = blockIdx.x * 64;
    int r = t >> 2, cq = (t & 3) << 4;
    unsigned short buf[16] __attribute__((aligned(16)));
#pragma unroll
    for (int j = 0; j < 16; j += 4) {
      float4 v = *reinterpret_cast<const float4*>(Tg + (size_t)(r0 + r) * D64 + cq + j);
      buf[j] = f2bf(v.x); buf[j + 1] = f2bf(v.y); buf[j + 2] = f2bf(v.z); buf[j + 3] = f2bf(v.w);
    }
#pragma unroll
    for (int j = 0; j < 16; ++j) tile[r][cq + j] = buf[j];
    *reinterpret_cast<ushort8*>(&rowmaj[(size_t)(r0 + r) * D64 + cq]) =
        *reinterpret_cast<ushort8*>(&buf[0]);
    *reinterpret_cast<ushort8*>(&rowmaj[(size_t)(r0 + r) * D64 + cq + 8]) =
        *reinterpret_cast<ushort8*>(&buf[8]);
    __syncthreads();
    int c = t >> 2, rq = (t & 3) << 4;
#pragma unroll
    for (int j = 0; j < 16; ++j) buf[j] = tile[rq + j][c];
    *reinterpret_cast<ushort8*>(&colmaj[(size_t)c * kNSH + r0 + rq]) =
        *reinterpret_cast<ushort8*>(&buf[0]);
    *reinterpret_cast<ushort8*>(&colmaj[(size_t)c * kNSH + r0 + rq + 8]) =
        *reinterpret_cast<ushort8*>(&buf[8]);
  }
}

// ======== MFMA: S=exp((tmp@tgt0^T)/T) -> Sbf, STbf (bf16), rs/cs (f32) ========
__global__ void expS_mfma(const unsigned short* __restrict__ Abf,
                          const unsigned short* __restrict__ Bbf,
                          unsigned short* __restrict__ Sbf, unsigned short* __restrict__ STbf,
                          float* __restrict__ rs, float* __restrict__ cs) {
  __shared__ unsigned short Cs[64][72];
  __shared__ float csred[4][64];
  int j0 = blockIdx.x * 64, i0 = blockIdx.y * 64;
  int t = threadIdx.x;
  int w = t >> 6, l = t & 63;
  int lr = l & 15, lk = (l >> 4) << 3;
  f32x4 acc[4] = {};
  const unsigned short* Ap = Abf + (size_t)(i0 + w * 16 + lr) * D64 + lk;
#pragma unroll
  for (int ks = 0; ks < 2; ++ks) {
    short8 a = *reinterpret_cast<const short8*>(Ap + ks * 32);
#pragma unroll
    for (int nt = 0; nt < 4; ++nt) {
      short8 b = *reinterpret_cast<const short8*>(
          Bbf + (size_t)(j0 + nt * 16 + lr) * D64 + ks * 32 + lk);
      acc[nt] = __builtin_amdgcn_mfma_f32_16x16x32_bf16(a, b, acc[nt], 0, 0, 0);
    }
  }
  float rowpart[4] = {0.f, 0.f, 0.f, 0.f};
#pragma unroll
  for (int nt = 0; nt < 4; ++nt) {
    float colpart = 0.f;
#pragma unroll
    for (int rg = 0; rg < 4; ++rg) {
      float e = __expf(acc[nt][rg] * kTinv);
      acc[nt][rg] = e;
      rowpart[rg] += e;
      colpart += e;
      Cs[w * 16 + (l >> 4) * 4 + rg][nt * 16 + lr] = f2bf(e);
    }
    float v = colpart;
    v += __shfl_xor(v, 16); v += __shfl_xor(v, 32);
    if (l < 16) csred[w][nt * 16 + l] = v;
  }
#pragma unroll
  for (int rg = 0; rg < 4; ++rg) {
    float v = rowpart[rg];
    v += __shfl_xor(v, 1); v += __shfl_xor(v, 2);
    v += __shfl_xor(v, 4); v += __shfl_xor(v, 8);
    if (lr == 0) atomicAdd(&rs[i0 + w * 16 + (l >> 4) * 4 + rg], v);
  }
  __syncthreads();
  if (t < 64) atomicAdd(&cs[j0 + t], csred[0][t] + csred[1][t] + csred[2][t] + csred[3][t]);
  {
    int r = t >> 2, cq = (t & 3) << 4;
    ushort8 v0 = *reinterpret_cast<const ushort8*>(&Cs[r][cq]);
    ushort8 v1 = *reinterpret_cast<const ushort8*>(&Cs[r][cq + 8]);
    *reinterpret_cast<ushort8*>(&Sbf[(size_t)(i0 + r) * kNSH + j0 + cq]) = v0;
    *reinterpret_cast<ushort8*>(&Sbf[(size_t)(i0 + r) * kNSH + j0 + cq + 8]) = v1;
    int c = t >> 2, rq = (t & 3) << 4;
    unsigned short buf[16] __attribute__((aligned(16)));
#pragma unroll
    for (int j = 0; j < 16; ++j) buf[j] = Cs[rq + j][c];
    *reinterpret_cast<ushort8*>(&STbf[(size_t)(j0 + c) * kNSH + i0 + rq]) =
        *reinterpret_cast<ushort8*>(&buf[0]);
    *reinterpret_cast<ushort8*>(&STbf[(size_t)(j0 + c) * kNSH + i0 + rq + 8]) =
        *reinterpret_cast<ushort8*>(&buf[8]);
  }
}

// ---- merged Ds/Dt row reduces ----
__global__ void rowred2(const unsigned short* __restrict__ Sbf, const float* __restrict__ cs,
                        float* __restrict__ Ds,
                        const unsigned short* __restrict__ STbf, const float* __restrict__ rs,
                        float* __restrict__ Dt) {
  const unsigned short* Sb = blockIdx.y ? STbf : Sbf;
  const float* w = blockIdx.y ? rs : cs;
  float* outp = blockIdx.y ? Dt : Ds;
  int i = blockIdx.x;
  const unsigned short* row = Sb + (size_t)i * kNSH;
  int t = threadIdx.x;
  float acc = 0.f;
  for (int j0 = t * 8; j0 < kNSH; j0 += 2048) {
    short8 v = *reinterpret_cast<const short8*>(row + j0);
#pragma unroll
    for (int j = 0; j < 8; ++j) acc += bf2f((unsigned short)v[j]) * w[j0 + j];
  }
#pragma unroll
  for (int o = 32; o; o >>= 1) acc += __shfl_xor(acc, o);
  __shared__ float red[4];
  if ((t & 63) == 0) red[t >> 6] = acc;
  __syncthreads();
  if (t == 0) outp[i] = red[0] + red[1] + red[2] + red[3] + 1.f;
}

// ======== dual-chain split-K MFMA skinny GEMM ========
__global__ void sgemm_bf(const unsigned short* __restrict__ aA, const unsigned short* __restrict__ xA,
                         float* __restrict__ pA,
                         const unsigned short* __restrict__ aB, const unsigned short* __restrict__ xB,
                         float* __restrict__ pB) {
  const unsigned short* A = (blockIdx.z == 0) ? aA : aB;
  const unsigned short* X = (blockIdx.z == 0) ? xA : xB;
  float* P = (blockIdx.z == 0) ? pA : pB;
  int t = threadIdx.x;
  int w = t >> 6, l = t & 63;
  int lr = l & 15, lk = (l >> 4) << 3;
  int m0 = blockIdx.x * 64 + w * 16;
  int k0 = blockIdx.y * 1024;
  f32x4 acc[4] = {};
  const unsigned short* Ap = A + (size_t)(m0 + lr) * kNSH + k0 + lk;
  const unsigned short* Xp = X + (size_t)lr * kNSH + k0 + lk;
  for (int ks = 0; ks < 32; ++ks) {
    short8 a = *reinterpret_cast<const short8*>(Ap + ks * 32);
#pragma unroll
    for (int nt = 0; nt < 4; ++nt) {
      short8 b = *reinterpret_cast<const short8*>(Xp + (size_t)nt * 16 * kNSH + ks * 32);
      acc[nt] = __builtin_amdgcn_mfma_f32_16x16x32_bf16(a, b, acc[nt], 0, 0, 0);
    }
  }
  float* Pp = P + ((size_t)blockIdx.y * kNSH + m0) * D64;
#pragma unroll
  for (int nt = 0; nt < 4; ++nt)
#pragma unroll
    for (int rg = 0; rg < 4; ++rg)
      Pp[(size_t)((l >> 4) * 4 + rg) * D64 + nt * 16 + lr] = acc[nt][rg];
}

// ======== split-K reduce + epilogue (dual-chain via blockIdx.y) ========
template <int EPI>
__global__ void red_epi(const float* __restrict__ pA, const float* __restrict__ addA,
                        const float* __restrict__ scA, float* __restrict__ outA,
                        unsigned short* __restrict__ outTA, const float* __restrict__ rawA,
                        unsigned short* __restrict__ rmA,
                        const float* __restrict__ pB, const float* __restrict__ addB,
                        const float* __restrict__ scB, float* __restrict__ outB,
                        unsigned short* __restrict__ outTB, const float* __restrict__ rawB,
                        unsigned short* __restrict__ rmB,
                        float* __restrict__ gout) {
  const float* p = (blockIdx.y == 0) ? pA : pB;
  const float* add = (blockIdx.y == 0) ? addA : addB;
  const float* sc = (blockIdx.y == 0) ? scA : scB;
  float* out = (blockIdx.y == 0) ? outA : outB;
  unsigned short* outT = (blockIdx.y == 0) ? outTA : outTB;
  const float* raw = (blockIdx.y == 0) ? rawA : rawB;
  unsigned short* rm = (blockIdx.y == 0) ? rmA : rmB;
  __shared__ unsigned short tile[64][4];
  int t = threadIdx.x;
  int d = t & 63, rl = t >> 6;
  int r = blockIdx.x * 4 + rl;
  size_t off = (size_t)r * D64 + d;
  const size_t SL = (size_t)kNSH * D64;
  float s = p[off] + p[SL + off] + p[2 * SL + off] + p[3 * SL + off];
  float v;
  if (EPI == 0) {
    v = s;
  } else if (EPI == 1) {
    v = add[off] + s / fmaxf(sc[r], 1e-12f);
    out[off] = v;
  } else {
    float x = fmaxf((s + add[off]) / sc[r], 0.f);
    float ss = x * x;
#pragma unroll
    for (int o = 32; o; o >>= 1) ss += __shfl_xor(ss, o);
    v = x / fmaxf(sqrtf(ss), 1e-12f);
    if (EPI == 2) out[off] = v;
    else {
      float fv = 0.5f * (raw[off] + v);
      rm[off] = f2bf(fv);
      float s2 = fv * fv;
#pragma unroll
      for (int o = 32; o; o >>= 1) s2 += __shfl_xor(s2, o);
      float nv = fv / fmaxf(sqrtf(s2), 1e-12f);
      size_t grow0 = (blockIdx.y == 0) ? 0 : (size_t)kNS;
      __builtin_nontemporal_store(nv, &gout[(grow0 + (size_t)r) * 256 + 64 + d]);
    }
  }
  if (EPI != 3) {
    tile[d][rl] = f2bf(v);
    __syncthreads();
    if (t < 64) {
      unsigned long long pk;
      unsigned short* pp = reinterpret_cast<unsigned short*>(&pk);
      pp[0] = tile[t][0]; pp[1] = tile[t][1]; pp[2] = tile[t][2]; pp[3] = tile[t][3];
      *reinterpret_cast<unsigned long long*>(&outT[(size_t)t * kNSH + blockIdx.x * 4]) = pk;
    }
  }
}

extern "C" void kernel_launch(void* const* d_in, const int* in_sizes, int n_in,
                              void* d_out, int out_size, void* d_ws, size_t ws_size,
                              hipStream_t stream) {
  const float* src_user = (const float*)d_in[0];
  const float* tgt_user = (const float*)d_in[1];
  const float* src_item = (const float*)d_in[2];
  const float* tgt_item = (const float*)d_in[3];
  const float* mapping  = (const float*)d_in[4];
  const float* s_vals   = (const float*)d_in[5];
  const float* t_vals   = (const float*)d_in[6];
  const int*   s_idx    = (const int*)d_in[7];
  const int*   t_idx    = (const int*)d_in[8];
  float* out = (float*)d_out;

  float* w = (float*)d_ws;
  size_t o = 0;
  float* es1h = w + o; o += (size_t)kNSH * D64;
  float* et1h = w + o; o += (size_t)kNSH * D64;
  float* src2 = w + o; o += (size_t)kNSH * D64;
  float* tgt2 = w + o; o += (size_t)kNSH * D64;
  float* itS  = w + o; o += (size_t)kNSH * D64;
  float* itT  = w + o; o += (size_t)kNSH * D64;
  float* partA = w + o; o += (size_t)4 * kNSH * D64;
  float* partB = w + o; o += (size_t)4 * kNSH * D64;
  float* rs = w + o; o += kNSH;
  float* cs = w + o; o += kNSH;
  float* Ds = w + o; o += kNSH;
  float* Dt = w + o; o += kNSH;
  // bf16 region
  unsigned short* ub = (unsigned short*)(w + o);
  size_t uo = 0;
  unsigned short* Sbf   = ub + uo; uo += (size_t)kNSH * kNSH;
  unsigned short* STbf  = ub + uo; uo += (size_t)kNSH * kNSH;
  unsigned short* tmpbf = ub + uo; uo += (size_t)kNSH * D64;
  unsigned short* tgtbf = ub + uo; uo += (size_t)kNSH * D64;
  unsigned short* tgtT  = ub + uo; uo += (size_t)kNSH * D64;
  unsigned short* src2T = ub + uo; uo += (size_t)kNSH * D64;
  unsigned short* tgt2T = ub + uo; uo += (size_t)kNSH * D64;
  unsigned short* itST  = ub + uo; uo += (size_t)kNSH * D64;
  unsigned short* itTT  = ub + uo; uo += (size_t)kNSH * D64;
  unsigned short* ybAT  = ub + uo; uo += (size_t)kNSH * D64;
  unsigned short* ybBT  = ub + uo; uo += (size_t)kNSH * D64;
  unsigned short* sub   = ub + uo; uo += (size_t)kNS * D64;
  unsigned short* tub   = ub + uo; uo += (size_t)kNT * D64;
  unsigned short* es1b  = ub + uo; uo += (size_t)kNS * D64;
  unsigned short* et1b  = ub + uo; uo += (size_t)kNT * D64;
  unsigned short* es2b  = ub + uo; uo += (size_t)kNS * D64;
  unsigned short* et2b  = ub + uo; uo += (size_t)kNT * D64;
  // int region
  int* iw = (int*)(ub + ((uo + 1) & ~(size_t)1));
  size_t io = 0;
  int* sPtr = iw + io; io += kNS;
  int* sEnd = iw + io; io += kNS;
  int* tPtr = iw + io; io += kNT;
  int* tEnd = iw + io; io += kNT;
  int* bCur = iw + io; io += 2048;
  io = (io + 1) & ~(size_t)1;
  const size_t kPad = (size_t)544 * kBStride;  // padded edges per graph
  int2* sEV = (int2*)(iw + io); io += 2 * kPad;
  int2* tEV = (int2*)(iw + io); io += 2 * kPad;
  int2* sCV = (int2*)(iw + io); io += 2 * kPad;
  int2* tCV = (int2*)(iw + io); io += 2 * kPad;

  const int bgrid = (kNNZ + kBinCh - 1) / kBinCh;

  // ---- CSR build: init cursors -> LDS bin (fixed-stride buckets) -> per-bucket CSR ----
  init_misc<<<16, 256, 0, stream>>>(bCur, rs, cs);
  bin_lds<<<dim3(bgrid, 2), 256, 0, stream>>>(s_idx, s_vals, t_idx, t_vals, bCur, sCV, tCV);
  bucket_csr<<<dim3(kNBkS, 2), 256, 0, stream>>>(sCV, sPtr, sEnd, sEV,
                                                 tCV, tPtr, tEnd, tEV, bCur);

  // ---- raw block-0 store + bf16 input copies ----
  cvt_in<<<(kNS + kNT + 15) / 16, 256, 0, stream>>>(src_user, src_item, tgt_user, tgt_item,
                                                    sub, tub, out);

  // ---- layer 1 spmm ----
  spmm1<<<(kNS + kNT + 31) / 32, 256, 0, stream>>>(sPtr, sEnd, sEV, tPtr, tEnd, tEV,
                                                   sub, tub, es1h, et1h, es1b, et1b, out);

  // ---- inter block ----
  prep_inter<<<dim3(256, 2), 256, 0, stream>>>(es1h, mapping, tmpbf, et1h, tgtbf, tgtT);
  expS_mfma<<<dim3(64, 64), 256, 0, stream>>>(tmpbf, tgtbf, Sbf, STbf, rs, cs);
  rowred2<<<dim3(kNSH, 2), 256, 0, stream>>>(Sbf, cs, Ds, STbf, rs, Dt);
  // src2 = src0 + (S@tgt0)/rs
  sgemm_bf<<<dim3(64, 4, 1), 256, 0, stream>>>(Sbf, tgtT, partA, Sbf, tgtT, partA);
  red_epi<1><<<dim3(1024, 1), 256, 0, stream>>>(partA, es1h, rs, src2, src2T, nullptr, nullptr,
                                                partA, es1h, rs, src2, src2T, nullptr, nullptr, out);
  // tgt2 = tgt0 + (S^T@src2)/cs
  sgemm_bf<<<dim3(64, 4, 1), 256, 0, stream>>>(STbf, src2T, partA, STbf, src2T, partA);
  red_epi<1><<<dim3(1024, 1), 256, 0, stream>>>(partA, et1h, cs, tgt2, tgt2T, nullptr, nullptr,
                                                partA, et1h, cs, tgt2, tgt2T, nullptr, nullptr, out);
  // 3 propagation iterations, dual-chain batched split-K
  float* paF = src2; unsigned short* paT = src2T;
  float* pbF = itS;  unsigned short* pbT = itST;
  float* qaF = tgt2; unsigned short* qaT = tgt2T;
  float* qbF = itT;  unsigned short* qbT = itTT;
  for (int itn = 0; itn < 3; ++itn) {
    sgemm_bf<<<dim3(64, 4, 2), 256, 0, stream>>>(STbf, paT, partA, Sbf, qaT, partB);
    red_epi<0><<<dim3(1024, 2), 256, 0, stream>>>(
        partA, nullptr, nullptr, nullptr, ybAT, nullptr, nullptr,
        partB, nullptr, nullptr, nullptr, ybBT, nullptr, nullptr, out);
    sgemm_bf<<<dim3(64, 4, 2), 256, 0, stream>>>(Sbf, ybAT, partA, STbf, ybBT, partB);
    if (itn < 2) {
      red_epi<2><<<dim3(1024, 2), 256, 0, stream>>>(
          partA, paF, Ds, pbF, pbT, nullptr, nullptr,
          partB, qaF, Dt, qbF, qbT, nullptr, nullptr, out);
      float* tf = paF; paF = pbF; pbF = tf;
      unsigned short* tt = paT; paT = pbT; pbT = tt;
      tf = qaF; qaF = qbF; qbF = tf;
      tt = qaT; qaT = qbT; qbT = tt;
    } else {
      red_epi<3><<<dim3(1024, 2), 256, 0, stream>>>(
          partA, paF, Ds, nullptr, nullptr, es1h, es1b,
          partB, qaF, Dt, nullptr, nullptr, et1h, et1b, out);
    }
  }

  // ---- layer 2 ----
  spmm23<1><<<(kNS + kNT + 31) / 32, 256, 0, stream>>>(sPtr, sEnd, sEV, tPtr, tEnd, tEV,
                                                       es1b, et1b, es2b, et2b, out, 128);
  // ---- layer 3 ----
  spmm23<0><<<(kNS + kNT + 31) / 32, 256, 0, stream>>>(sPtr, sEnd, sEV, tPtr, tEnd, tEV,
                                                       es2b, et2b, nullptr, nullptr, out, 192);
}